// Round 6
// baseline (408.784 us; speedup 1.0000x reference)
//
#include <hip/hip_runtime.h>
#include <hip/hip_bf16.h>

// Problem constants
#define B_  16
#define L_  1024
#define F_  512
#define H_  8
#define D_  64
#define M_  (B_ * L_)    // 16384 rows
#define HD_ 512

typedef __bf16 bf16x8 __attribute__((ext_vector_type(8)));
typedef __bf16 bf16x4 __attribute__((ext_vector_type(4)));
typedef short  s16x4  __attribute__((ext_vector_type(4)));
typedef float  f32x4  __attribute__((ext_vector_type(4)));

// Async global->LDS, 16B per lane. LDS dest must be wave-uniform base + lane*16.
__device__ __forceinline__ void gl_lds16(const void* g, void* l) {
  __builtin_amdgcn_global_load_lds(
      (const __attribute__((address_space(1))) unsigned int*)g,
      (__attribute__((address_space(3))) unsigned int*)l, 16, 0, 0);
}

// ---------------------------------------------------------------------------
// Weight prep: Wt[n][k] = (bf16) W[k][n]  for Wq,Wk,Wv,Wo (each 512x512).
// ---------------------------------------------------------------------------
__global__ __launch_bounds__(256) void wt_kernel(
    const float* __restrict__ Wq, const float* __restrict__ Wk,
    const float* __restrict__ Wv, const float* __restrict__ Wo,
    __bf16* __restrict__ Wt_all)
{
  const float* W = (blockIdx.z == 0) ? Wq : (blockIdx.z == 1) ? Wk
                 : (blockIdx.z == 2) ? Wv : Wo;
  __bf16* Wt = Wt_all + (size_t)blockIdx.z * (512 * 512);
  __shared__ float s[32][33];
  const int t = threadIdx.x;
  const int r = t >> 5, c = t & 31;
  const int k0 = blockIdx.x * 32, n0 = blockIdx.y * 32;
#pragma unroll
  for (int i = 0; i < 4; ++i)
    s[r + i * 8][c] = W[(size_t)(k0 + r + i * 8) * 512 + n0 + c];
  __syncthreads();
#pragma unroll
  for (int i = 0; i < 4; ++i)
    Wt[(size_t)(n0 + r + i * 8) * 512 + k0 + c] = (__bf16)s[c][r + i * 8];
}

// ---------------------------------------------------------------------------
// Merged projection GEMM (q, k, v in one launch).
// seg = blockIdx.y>>2: 0->q (X=inputs_q), 1->k, 2->v (X=inputs_kv).
// seg 0/1: dst layout (B,H,L,D);  seg 2: dst (B,H,D,L).
// ---------------------------------------------------------------------------
__global__ __launch_bounds__(256) void gemm_proj_kernel(
    const float* __restrict__ Xq, const float* __restrict__ Xkv,
    const __bf16* __restrict__ Wt_all,
    const float* __restrict__ bq, const float* __restrict__ bk_,
    const float* __restrict__ bv_,
    __bf16* __restrict__ qd, __bf16* __restrict__ kd, __bf16* __restrict__ vd)
{
  const int seg = blockIdx.y >> 2;
  const float* X = (seg == 0) ? Xq : Xkv;
  const __bf16* Wt = Wt_all + (size_t)seg * 262144;
  const float* bias = (seg == 0) ? bq : (seg == 1) ? bk_ : bv_;
  __bf16* dst = (seg == 0) ? qd : (seg == 1) ? kd : vd;
  const int mode = seg;

  __shared__ __align__(16) __bf16 As[4][128][8];
  __shared__ __align__(16) __bf16 Bs[4][128][8];
  const int t = threadIdx.x;
  const int m0 = blockIdx.x * 128, n0 = (blockIdx.y & 3) * 128;
  const int lane = t & 63, w = t >> 6;
  const int ml = lane & 15, quad = lane >> 4;
  const int wm = w & 1, wn = w >> 1;

  f32x4 acc[4][4];
#pragma unroll
  for (int i = 0; i < 4; ++i)
#pragma unroll
    for (int j = 0; j < 4; ++j) acc[i][j] = (f32x4){0.f, 0.f, 0.f, 0.f};

  for (int k0 = 0; k0 < 512; k0 += 32) {
    __syncthreads();
    // B tile via async DMA (coalesced: 8-lane groups cover a 128B row chunk)
#pragma unroll
    for (int i = 0; i < 2; ++i) {
      int slot = (w + i * 4) * 64 + lane;
      int ko = slot >> 7, row = slot & 127;
      gl_lds16(&Wt[(size_t)(n0 + row) * 512 + k0 + ko * 8], &Bs[ko][row][0]);
    }
    // A tile: load fp32, convert, ds_write (overlaps B DMA latency)
#pragma unroll
    for (int i = 0; i < 2; ++i) {
      int slot = t + i * 256;
      int ko = slot & 3, row = slot >> 2;
      const float* src = X + (size_t)(m0 + row) * 512 + k0 + ko * 8;
      float4 f0 = *(const float4*)src;
      float4 f1 = *(const float4*)(src + 4);
      bf16x8 v;
      v[0] = (__bf16)f0.x; v[1] = (__bf16)f0.y; v[2] = (__bf16)f0.z; v[3] = (__bf16)f0.w;
      v[4] = (__bf16)f1.x; v[5] = (__bf16)f1.y; v[6] = (__bf16)f1.z; v[7] = (__bf16)f1.w;
      *(bf16x8*)&As[ko][row][0] = v;
    }
    __syncthreads();
    bf16x8 a[4], b[4];
#pragma unroll
    for (int mt = 0; mt < 4; ++mt)
      a[mt] = *(const bf16x8*)&As[quad][wm * 64 + mt * 16 + ml][0];
#pragma unroll
    for (int nt = 0; nt < 4; ++nt)
      b[nt] = *(const bf16x8*)&Bs[quad][wn * 64 + nt * 16 + ml][0];
#pragma unroll
    for (int mt = 0; mt < 4; ++mt)
#pragma unroll
      for (int nt = 0; nt < 4; ++nt)
        acc[mt][nt] =
            __builtin_amdgcn_mfma_f32_16x16x32_bf16(a[mt], b[nt], acc[mt][nt], 0, 0, 0);
  }

#pragma unroll
  for (int nt = 0; nt < 4; ++nt) {
    int col = n0 + wn * 64 + nt * 16 + ml;
    float bv = bias[col];
    int h = col >> 6, d = col & 63;
#pragma unroll
    for (int mt = 0; mt < 4; ++mt) {
      int row0 = m0 + wm * 64 + mt * 16 + quad * 4;
      int bz = row0 >> 10;
      int l0 = row0 & 1023;
      if (mode == 2) {
        bf16x4 pk;
#pragma unroll
        for (int r = 0; r < 4; ++r) pk[r] = (__bf16)(acc[mt][nt][r] + bv);
        size_t idx = ((size_t)(bz * H_ + h) * D_ + d) * L_ + l0;
        *(bf16x4*)&dst[idx] = pk;
      } else {
        size_t base = ((size_t)(bz * H_ + h) * L_ + l0) * D_ + d;
#pragma unroll
        for (int r = 0; r < 4; ++r)
          dst[base + (size_t)r * D_] = (__bf16)(acc[mt][nt][r] + bv);
      }
    }
  }
}

// ---------------------------------------------------------------------------
// Flash attention v5b. One block per (q-tile 256, h, b); 4 waves, wave owns
// 64 q (4x16). K and V double-buffered in LDS (XOR-swizzled coalesced DMA).
//
// Key trick: S^T C-layout residue (lane holds q=ml, keys quad*4+r) IS the
// A-operand layout of v_mfma_f32_16x16x16_bf16 (A[m=lane&15][k=quad*4+j]).
// So P never round-trips through LDS: exp results are packed to bf16x4 in
// registers and fed straight into K=16 PV MFMAs (builtin name: *_1k, v4i16
// operands). V fragments are b64 reads (4 keys) from the swizzled Vs tile.
// No Ps buffer, no transpose barrier.
// ---------------------------------------------------------------------------
__global__ __launch_bounds__(256, 3) void attn_kernel(
    const __bf16* __restrict__ qg,    // [B][H][L][D]
    const __bf16* __restrict__ kg,    // [B][H][L][D]
    const __bf16* __restrict__ vg,    // [B][H][D][L]
    const float* __restrict__ toep_g, // [H][4096]
    __bf16* __restrict__ xg)          // [B*L][512]
{
  __shared__ float toep[4096];                   // 16 KB
  __shared__ __align__(16) __bf16 Ks[2][64][64]; // 2 x 8 KB (swizzled)
  __shared__ __align__(16) __bf16 Vs[2][64][64]; // 2 x 8 KB (swizzled)

  const int t = threadIdx.x;
  const int n = blockIdx.x;
  // XCD swizzle: the 4 q-tiles sharing one (b,h) land on the same XCD.
  const int bh = ((n >> 5) << 3) | (n & 7);
  const int q0 = ((n >> 3) & 3) * 256;
  const int h = bh & 7;
  const int lane = t & 63, w = t >> 6;
  const int ml = lane & 15, quad = lane >> 4;
  const int lo3 = lane >> 3;        // 0..7 (== row&7 for staging rows)
  const int kop = lane & 7;         // LDS 16B-chunk slot

  const size_t qkbase = (size_t)bh * (L_ * D_);
  const size_t vbase  = (size_t)bh * (D_ * L_);

  // toeplitz table for this head -> LDS
  {
    const float4* src = (const float4*)(toep_g + (size_t)h * 4096);
    float4* dl = (float4*)toep;
    for (int i = t; i < 1024; i += 256) dl[i] = src[i];
  }

  // stage K,V tile 0 (coalesced swizzled DMA)
#pragma unroll
  for (int i = 0; i < 2; ++i) {
    int row = (w * 2 + i) * 8 + lo3;
    int ko = kop ^ lo3;
    gl_lds16(&kg[qkbase + (size_t)row * D_ + ko * 8], &Ks[0][row][kop * 8]);
    gl_lds16(&vg[vbase + (size_t)row * L_ + ko * 8], &Vs[0][row][kop * 8]);
  }

  // Q B-fragments, 4 q-subtiles, registers for the whole kernel (32 VGPR)
  bf16x8 qf[4][2];
#pragma unroll
  for (int qn = 0; qn < 4; ++qn) {
    const __bf16* qp =
        qg + qkbase + (size_t)(q0 + w * 64 + qn * 16 + ml) * D_ + quad * 8;
    qf[qn][0] = *(const bf16x8*)qp;
    qf[qn][1] = *(const bf16x8*)(qp + 32);
  }

  float lpart[4] = {0.f, 0.f, 0.f, 0.f};
  f32x4 o[4][4];
#pragma unroll
  for (int qn = 0; qn < 4; ++qn)
#pragma unroll
    for (int dt = 0; dt < 4; ++dt) o[qn][dt] = (f32x4){0.f, 0.f, 0.f, 0.f};

  __syncthreads();  // toep + tile 0 ready (barrier drains vmcnt)

  int cur = 0;
  for (int k0 = 0; k0 < L_; k0 += 64) {
    // ---- stage NEXT K,V tile (async, consumed after the end barrier) ----
    if (k0 + 64 < L_) {
      int nb = cur ^ 1;
#pragma unroll
      for (int i = 0; i < 2; ++i) {
        int row = (w * 2 + i) * 8 + lo3;
        int ko = kop ^ lo3;
        gl_lds16(&kg[qkbase + (size_t)(k0 + 64 + row) * D_ + ko * 8],
                 &Ks[nb][row][kop * 8]);
        gl_lds16(&vg[vbase + (size_t)row * L_ + k0 + 64 + ko * 8],
                 &Vs[nb][row][kop * 8]);
      }
    }

    // ---- per 16-key group: S^T -> bias+exp -> P frag (regs) -> PV ----
#pragma unroll
    for (int nt = 0; nt < 4; ++nt) {
      bf16x8 kf0 = *(const bf16x8*)&Ks[cur][nt * 16 + ml][(quad ^ (ml & 7)) * 8];
      bf16x8 kf1 =
          *(const bf16x8*)&Ks[cur][nt * 16 + ml][((4 + quad) ^ (ml & 7)) * 8];
      int kx = (k0 >> 5) + (nt >> 1);

      s16x4 pfrag[4];
#pragma unroll
      for (int qn = 0; qn < 4; ++qn) {
        f32x4 z = (f32x4){0.f, 0.f, 0.f, 0.f};
        z = __builtin_amdgcn_mfma_f32_16x16x32_bf16(kf0, qf[qn][0], z, 0, 0, 0);
        z = __builtin_amdgcn_mfma_f32_16x16x32_bf16(kf1, qf[qn][1], z, 0, 0, 0);

        int qb = w * 64 + qn * 16;
        int base = (((q0 + qb) >> 5) - kx + 32) * 64 +
                   ((qb & 31) + ml - ((nt & 1) * 16 + quad * 4) + 32);
        float p[4];
#pragma unroll
        for (int r = 0; r < 4; ++r)
          p[r] = __expf(fmaf(z[r], 0.125f, toep[base - r]));
        lpart[qn] += (p[0] + p[1]) + (p[2] + p[3]);
        bf16x4 pk;
#pragma unroll
        for (int r = 0; r < 4; ++r) pk[r] = (__bf16)p[r];
        pfrag[qn] = __builtin_bit_cast(s16x4, pk);
      }

      // PV for this 16-key group: K=16 MFMA, A=pfrag (regs), B=V b64 frags
#pragma unroll
      for (int dt = 0; dt < 4; ++dt) {
        int row = dt * 16 + ml;
        int gc = nt * 2 + (quad >> 1);
        bf16x4 vfr = *(const bf16x4*)
            &Vs[cur][row][((gc ^ (row & 7)) * 8) + (quad & 1) * 4];
        s16x4 vfs = __builtin_bit_cast(s16x4, vfr);
#pragma unroll
        for (int qn = 0; qn < 4; ++qn)
          o[qn][dt] = __builtin_amdgcn_mfma_f32_16x16x16bf16_1k(
              pfrag[qn], vfs, o[qn][dt], 0, 0, 0);
      }
    }

    __syncthreads();  // next tile staged + all reads of cur done
    cur ^= 1;
  }

  // ---- softmax denominators (per qn: sum the 4 quads sharing q=ml) ----
#pragma unroll
  for (int qn = 0; qn < 4; ++qn) {
    lpart[qn] += __shfl_xor(lpart[qn], 16);
    lpart[qn] += __shfl_xor(lpart[qn], 32);
  }
  float linv[4][4];
#pragma unroll
  for (int qn = 0; qn < 4; ++qn)
#pragma unroll
    for (int r = 0; r < 4; ++r)
      linv[qn][r] = 1.0f / __shfl(lpart[qn], quad * 16 + quad * 4 + r);

  // ---- epilogue: rows q = q0 + w*64 + qn*16 + quad*4 + r, cols dt*16+ml ----
#pragma unroll
  for (int qn = 0; qn < 4; ++qn)
#pragma unroll
    for (int dt = 0; dt < 4; ++dt)
#pragma unroll
      for (int r = 0; r < 4; ++r) {
        int row = q0 + w * 64 + qn * 16 + quad * 4 + r;
        xg[((size_t)(bh >> 3) * L_ + row) * 512 + h * 64 + dt * 16 + ml] =
            (__bf16)(o[qn][dt][r] * linv[qn][r]);
      }
}

// ---------------------------------------------------------------------------
// Output GEMM: out[16384,512] (fp32) = Xattn(bf16) @ Wo + bo.
// ---------------------------------------------------------------------------
__global__ __launch_bounds__(256) void gemm_out_kernel(
    const __bf16* __restrict__ Xb,
    const __bf16* __restrict__ Wt,
    const float* __restrict__ bo,
    float* __restrict__ out)
{
  __shared__ __align__(16) __bf16 As[4][128][8];
  __shared__ __align__(16) __bf16 Bs[4][128][8];
  const int t = threadIdx.x;
  const int m0 = blockIdx.x * 128, n0 = blockIdx.y * 128;
  const int lane = t & 63, w = t >> 6;
  const int ml = lane & 15, quad = lane >> 4;
  const int wm = w & 1, wn = w >> 1;

  f32x4 acc[4][4];
#pragma unroll
  for (int i = 0; i < 4; ++i)
#pragma unroll
    for (int j = 0; j < 4; ++j) acc[i][j] = (f32x4){0.f, 0.f, 0.f, 0.f};

  for (int k0 = 0; k0 < 512; k0 += 32) {
    __syncthreads();
#pragma unroll
    for (int i = 0; i < 2; ++i) {
      int slot = (w + i * 4) * 64 + lane;
      int ko = slot >> 7, row = slot & 127;
      gl_lds16(&Xb[(size_t)(m0 + row) * 512 + k0 + ko * 8], &As[ko][row][0]);
      gl_lds16(&Wt[(size_t)(n0 + row) * 512 + k0 + ko * 8], &Bs[ko][row][0]);
    }
    __syncthreads();
    bf16x8 a[4], b[4];
#pragma unroll
    for (int mt = 0; mt < 4; ++mt)
      a[mt] = *(const bf16x8*)&As[quad][wm * 64 + mt * 16 + ml][0];
#pragma unroll
    for (int nt = 0; nt < 4; ++nt)
      b[nt] = *(const bf16x8*)&Bs[quad][wn * 64 + nt * 16 + ml][0];
#pragma unroll
    for (int mt = 0; mt < 4; ++mt)
#pragma unroll
      for (int nt = 0; nt < 4; ++nt)
        acc[mt][nt] =
            __builtin_amdgcn_mfma_f32_16x16x32_bf16(a[mt], b[nt], acc[mt][nt], 0, 0, 0);
  }

#pragma unroll
  for (int nt = 0; nt < 4; ++nt) {
    int col = n0 + wn * 64 + nt * 16 + ml;
    float bv = bo[col];
#pragma unroll
    for (int mt = 0; mt < 4; ++mt) {
      int row0 = m0 + wm * 64 + mt * 16 + quad * 4;
#pragma unroll
      for (int r = 0; r < 4; ++r)
        out[(size_t)(row0 + r) * 512 + col] = acc[mt][nt][r] + bv;
    }
  }
}

// ---------------------------------------------------------------------------
extern "C" void kernel_launch(void* const* d_in, const int* in_sizes, int n_in,
                              void* d_out, int out_size, void* d_ws, size_t ws_size,
                              hipStream_t stream) {
  const float* inputs_q  = (const float*)d_in[0];
  const float* inputs_kv = (const float*)d_in[1];
  const float* Wq = (const float*)d_in[2];
  const float* bq = (const float*)d_in[3];
  const float* Wk = (const float*)d_in[4];
  const float* bk = (const float*)d_in[5];
  const float* Wv = (const float*)d_in[6];
  const float* bv = (const float*)d_in[7];
  const float* Wo = (const float*)d_in[8];
  const float* bo = (const float*)d_in[9];
  const float* toep = (const float*)d_in[10];
  float* out = (float*)d_out;

  char* ws = (char*)d_ws;
  __bf16* qb = (__bf16*)(ws);
  __bf16* kb = (__bf16*)(ws + 16777216);
  __bf16* vb = (__bf16*)(ws + 33554432);
  __bf16* xb = (__bf16*)(ws + 50331648);
  __bf16* Wt = (__bf16*)(ws + 67108864);

  wt_kernel<<<dim3(16, 16, 4), 256, 0, stream>>>(Wq, Wk, Wv, Wo, Wt);
  gemm_proj_kernel<<<dim3(128, 12), 256, 0, stream>>>(
      inputs_q, inputs_kv, Wt, bq, bk, bv, qb, kb, vb);
  attn_kernel<<<dim3(512), 256, 0, stream>>>(qb, kb, vb, toep, xb);
  gemm_out_kernel<<<dim3(128, 4), 256, 0, stream>>>(xb, Wt + 3 * 262144, bo, out);
}

// Round 7
// 251.562 us; speedup vs baseline: 1.6250x; 1.6250x over previous
//
#include <hip/hip_runtime.h>
#include <hip/hip_bf16.h>

// Problem constants
#define B_  16
#define L_  1024
#define F_  512
#define H_  8
#define D_  64
#define M_  (B_ * L_)    // 16384 rows
#define HD_ 512

typedef __bf16 bf16x8 __attribute__((ext_vector_type(8)));
typedef __bf16 bf16x4 __attribute__((ext_vector_type(4)));
typedef short  s16x4  __attribute__((ext_vector_type(4)));
typedef float  f32x4  __attribute__((ext_vector_type(4)));

// Async global->LDS, 16B per lane. LDS dest must be wave-uniform base + lane*16.
__device__ __forceinline__ void gl_lds16(const void* g, void* l) {
  __builtin_amdgcn_global_load_lds(
      (const __attribute__((address_space(1))) unsigned int*)g,
      (__attribute__((address_space(3))) unsigned int*)l, 16, 0, 0);
}

// ---------------------------------------------------------------------------
// Weight prep: Wt[n][k] = (bf16) W[k][n]  for Wq,Wk,Wv,Wo (each 512x512).
// ---------------------------------------------------------------------------
__global__ __launch_bounds__(256) void wt_kernel(
    const float* __restrict__ Wq, const float* __restrict__ Wk,
    const float* __restrict__ Wv, const float* __restrict__ Wo,
    __bf16* __restrict__ Wt_all)
{
  const float* W = (blockIdx.z == 0) ? Wq : (blockIdx.z == 1) ? Wk
                 : (blockIdx.z == 2) ? Wv : Wo;
  __bf16* Wt = Wt_all + (size_t)blockIdx.z * (512 * 512);
  __shared__ float s[32][33];
  const int t = threadIdx.x;
  const int r = t >> 5, c = t & 31;
  const int k0 = blockIdx.x * 32, n0 = blockIdx.y * 32;
#pragma unroll
  for (int i = 0; i < 4; ++i)
    s[r + i * 8][c] = W[(size_t)(k0 + r + i * 8) * 512 + n0 + c];
  __syncthreads();
#pragma unroll
  for (int i = 0; i < 4; ++i)
    Wt[(size_t)(n0 + r + i * 8) * 512 + k0 + c] = (__bf16)s[c][r + i * 8];
}

// ---------------------------------------------------------------------------
// Merged projection GEMM (q, k, v in one launch).
// seg = blockIdx.y>>2: 0->q (X=inputs_q), 1->k, 2->v (X=inputs_kv).
// seg 0/1: dst layout (B,H,L,D);  seg 2: dst (B,H,D,L).
// ---------------------------------------------------------------------------
__global__ __launch_bounds__(256) void gemm_proj_kernel(
    const float* __restrict__ Xq, const float* __restrict__ Xkv,
    const __bf16* __restrict__ Wt_all,
    const float* __restrict__ bq, const float* __restrict__ bk_,
    const float* __restrict__ bv_,
    __bf16* __restrict__ qd, __bf16* __restrict__ kd, __bf16* __restrict__ vd)
{
  const int seg = blockIdx.y >> 2;
  const float* X = (seg == 0) ? Xq : Xkv;
  const __bf16* Wt = Wt_all + (size_t)seg * 262144;
  const float* bias = (seg == 0) ? bq : (seg == 1) ? bk_ : bv_;
  __bf16* dst = (seg == 0) ? qd : (seg == 1) ? kd : vd;
  const int mode = seg;

  __shared__ __align__(16) __bf16 As[4][128][8];
  __shared__ __align__(16) __bf16 Bs[4][128][8];
  const int t = threadIdx.x;
  const int m0 = blockIdx.x * 128, n0 = (blockIdx.y & 3) * 128;
  const int lane = t & 63, w = t >> 6;
  const int ml = lane & 15, quad = lane >> 4;
  const int wm = w & 1, wn = w >> 1;

  f32x4 acc[4][4];
#pragma unroll
  for (int i = 0; i < 4; ++i)
#pragma unroll
    for (int j = 0; j < 4; ++j) acc[i][j] = (f32x4){0.f, 0.f, 0.f, 0.f};

  for (int k0 = 0; k0 < 512; k0 += 32) {
    __syncthreads();
    // B tile via async DMA (coalesced: 8-lane groups cover a 128B row chunk)
#pragma unroll
    for (int i = 0; i < 2; ++i) {
      int slot = (w + i * 4) * 64 + lane;
      int ko = slot >> 7, row = slot & 127;
      gl_lds16(&Wt[(size_t)(n0 + row) * 512 + k0 + ko * 8], &Bs[ko][row][0]);
    }
    // A tile: load fp32, convert, ds_write (overlaps B DMA latency)
#pragma unroll
    for (int i = 0; i < 2; ++i) {
      int slot = t + i * 256;
      int ko = slot & 3, row = slot >> 2;
      const float* src = X + (size_t)(m0 + row) * 512 + k0 + ko * 8;
      float4 f0 = *(const float4*)src;
      float4 f1 = *(const float4*)(src + 4);
      bf16x8 v;
      v[0] = (__bf16)f0.x; v[1] = (__bf16)f0.y; v[2] = (__bf16)f0.z; v[3] = (__bf16)f0.w;
      v[4] = (__bf16)f1.x; v[5] = (__bf16)f1.y; v[6] = (__bf16)f1.z; v[7] = (__bf16)f1.w;
      *(bf16x8*)&As[ko][row][0] = v;
    }
    __syncthreads();
    bf16x8 a[4], b[4];
#pragma unroll
    for (int mt = 0; mt < 4; ++mt)
      a[mt] = *(const bf16x8*)&As[quad][wm * 64 + mt * 16 + ml][0];
#pragma unroll
    for (int nt = 0; nt < 4; ++nt)
      b[nt] = *(const bf16x8*)&Bs[quad][wn * 64 + nt * 16 + ml][0];
#pragma unroll
    for (int mt = 0; mt < 4; ++mt)
#pragma unroll
      for (int nt = 0; nt < 4; ++nt)
        acc[mt][nt] =
            __builtin_amdgcn_mfma_f32_16x16x32_bf16(a[mt], b[nt], acc[mt][nt], 0, 0, 0);
  }

#pragma unroll
  for (int nt = 0; nt < 4; ++nt) {
    int col = n0 + wn * 64 + nt * 16 + ml;
    float bv = bias[col];
    int h = col >> 6, d = col & 63;
#pragma unroll
    for (int mt = 0; mt < 4; ++mt) {
      int row0 = m0 + wm * 64 + mt * 16 + quad * 4;
      int bz = row0 >> 10;
      int l0 = row0 & 1023;
      if (mode == 2) {
        bf16x4 pk;
#pragma unroll
        for (int r = 0; r < 4; ++r) pk[r] = (__bf16)(acc[mt][nt][r] + bv);
        size_t idx = ((size_t)(bz * H_ + h) * D_ + d) * L_ + l0;
        *(bf16x4*)&dst[idx] = pk;
      } else {
        size_t base = ((size_t)(bz * H_ + h) * L_ + l0) * D_ + d;
#pragma unroll
        for (int r = 0; r < 4; ++r)
          dst[base + (size_t)r * D_] = (__bf16)(acc[mt][nt][r] + bv);
      }
    }
  }
}

// ---------------------------------------------------------------------------
// Flash attention v5c. One block per (q-tile 256, h, b); 4 waves, wave owns
// 64 q (4x16). K and V double-buffered in LDS (XOR-swizzled coalesced DMA).
//
// P never round-trips through LDS: S^T C-layout residue (q=ml, key=quad*4+r)
// IS the A-operand layout of v_mfma_f32_16x16x16_bf16, so exp results feed
// straight into K=16 PV MFMAs. V fragments are b64 reads from swizzled Vs.
//
// launch_bounds(256,2): grid is 512 blocks / 256 CUs = 2 blocks/CU max, so
// min-2-waves/EU is the true occupancy target; (256,3) capped VGPR at 84 and
// spilled the 64-VGPR accumulator array to scratch (408 MB of HBM writes).
// ---------------------------------------------------------------------------
__global__ __launch_bounds__(256, 2) void attn_kernel(
    const __bf16* __restrict__ qg,    // [B][H][L][D]
    const __bf16* __restrict__ kg,    // [B][H][L][D]
    const __bf16* __restrict__ vg,    // [B][H][D][L]
    const float* __restrict__ toep_g, // [H][4096]
    __bf16* __restrict__ xg)          // [B*L][512]
{
  __shared__ float toep[4096];                   // 16 KB
  __shared__ __align__(16) __bf16 Ks[2][64][64]; // 2 x 8 KB (swizzled)
  __shared__ __align__(16) __bf16 Vs[2][64][64]; // 2 x 8 KB (swizzled)

  const int t = threadIdx.x;
  const int n = blockIdx.x;
  // XCD swizzle: the 4 q-tiles sharing one (b,h) land on the same XCD.
  const int bh = ((n >> 5) << 3) | (n & 7);
  const int q0 = ((n >> 3) & 3) * 256;
  const int h = bh & 7;
  const int lane = t & 63, w = t >> 6;
  const int ml = lane & 15, quad = lane >> 4;
  const int lo3 = lane >> 3;        // 0..7 (== row&7 for staging rows)
  const int kop = lane & 7;         // LDS 16B-chunk slot

  const size_t qkbase = (size_t)bh * (L_ * D_);
  const size_t vbase  = (size_t)bh * (D_ * L_);

  // toeplitz table for this head -> LDS
  {
    const float4* src = (const float4*)(toep_g + (size_t)h * 4096);
    float4* dl = (float4*)toep;
    for (int i = t; i < 1024; i += 256) dl[i] = src[i];
  }

  // stage K,V tile 0 (coalesced swizzled DMA)
#pragma unroll
  for (int i = 0; i < 2; ++i) {
    int row = (w * 2 + i) * 8 + lo3;
    int ko = kop ^ lo3;
    gl_lds16(&kg[qkbase + (size_t)row * D_ + ko * 8], &Ks[0][row][kop * 8]);
    gl_lds16(&vg[vbase + (size_t)row * L_ + ko * 8], &Vs[0][row][kop * 8]);
  }

  // Q B-fragments, 4 q-subtiles, registers for the whole kernel (32 VGPR)
  bf16x8 qf[4][2];
#pragma unroll
  for (int qn = 0; qn < 4; ++qn) {
    const __bf16* qp =
        qg + qkbase + (size_t)(q0 + w * 64 + qn * 16 + ml) * D_ + quad * 8;
    qf[qn][0] = *(const bf16x8*)qp;
    qf[qn][1] = *(const bf16x8*)(qp + 32);
  }

  float lpart[4] = {0.f, 0.f, 0.f, 0.f};
  f32x4 o[4][4];
#pragma unroll
  for (int qn = 0; qn < 4; ++qn)
#pragma unroll
    for (int dt = 0; dt < 4; ++dt) o[qn][dt] = (f32x4){0.f, 0.f, 0.f, 0.f};

  __syncthreads();  // toep + tile 0 ready (barrier drains vmcnt)

  int cur = 0;
  for (int k0 = 0; k0 < L_; k0 += 64) {
    // ---- stage NEXT K,V tile (async, consumed after the end barrier) ----
    if (k0 + 64 < L_) {
      int nb = cur ^ 1;
#pragma unroll
      for (int i = 0; i < 2; ++i) {
        int row = (w * 2 + i) * 8 + lo3;
        int ko = kop ^ lo3;
        gl_lds16(&kg[qkbase + (size_t)(k0 + 64 + row) * D_ + ko * 8],
                 &Ks[nb][row][kop * 8]);
        gl_lds16(&vg[vbase + (size_t)row * L_ + k0 + 64 + ko * 8],
                 &Vs[nb][row][kop * 8]);
      }
    }

    // ---- per 16-key group: S^T -> bias+exp -> P frag (regs) -> PV ----
#pragma unroll
    for (int nt = 0; nt < 4; ++nt) {
      bf16x8 kf0 = *(const bf16x8*)&Ks[cur][nt * 16 + ml][(quad ^ (ml & 7)) * 8];
      bf16x8 kf1 =
          *(const bf16x8*)&Ks[cur][nt * 16 + ml][((4 + quad) ^ (ml & 7)) * 8];
      int kx = (k0 >> 5) + (nt >> 1);

      s16x4 pfrag[4];
#pragma unroll
      for (int qn = 0; qn < 4; ++qn) {
        f32x4 z = (f32x4){0.f, 0.f, 0.f, 0.f};
        z = __builtin_amdgcn_mfma_f32_16x16x32_bf16(kf0, qf[qn][0], z, 0, 0, 0);
        z = __builtin_amdgcn_mfma_f32_16x16x32_bf16(kf1, qf[qn][1], z, 0, 0, 0);

        int qb = w * 64 + qn * 16;
        int base = (((q0 + qb) >> 5) - kx + 32) * 64 +
                   ((qb & 31) + ml - ((nt & 1) * 16 + quad * 4) + 32);
        float p[4];
#pragma unroll
        for (int r = 0; r < 4; ++r)
          p[r] = __expf(fmaf(z[r], 0.125f, toep[base - r]));
        lpart[qn] += (p[0] + p[1]) + (p[2] + p[3]);
        bf16x4 pk;
#pragma unroll
        for (int r = 0; r < 4; ++r) pk[r] = (__bf16)p[r];
        pfrag[qn] = __builtin_bit_cast(s16x4, pk);
      }

      // PV for this 16-key group: K=16 MFMA, A=pfrag (regs), B=V b64 frags
#pragma unroll
      for (int dt = 0; dt < 4; ++dt) {
        int row = dt * 16 + ml;
        int gc = nt * 2 + (quad >> 1);
        bf16x4 vfr = *(const bf16x4*)
            &Vs[cur][row][((gc ^ (row & 7)) * 8) + (quad & 1) * 4];
        s16x4 vfs = __builtin_bit_cast(s16x4, vfr);
#pragma unroll
        for (int qn = 0; qn < 4; ++qn)
          o[qn][dt] = __builtin_amdgcn_mfma_f32_16x16x16bf16_1k(
              pfrag[qn], vfs, o[qn][dt], 0, 0, 0);
      }
    }

    __syncthreads();  // next tile staged + all reads of cur done
    cur ^= 1;
  }

  // ---- softmax denominators (per qn: sum the 4 quads sharing q=ml) ----
#pragma unroll
  for (int qn = 0; qn < 4; ++qn) {
    lpart[qn] += __shfl_xor(lpart[qn], 16);
    lpart[qn] += __shfl_xor(lpart[qn], 32);
  }
  float linv[4][4];
#pragma unroll
  for (int qn = 0; qn < 4; ++qn)
#pragma unroll
    for (int r = 0; r < 4; ++r)
      linv[qn][r] = 1.0f / __shfl(lpart[qn], quad * 16 + quad * 4 + r);

  // ---- epilogue: rows q = q0 + w*64 + qn*16 + quad*4 + r, cols dt*16+ml ----
#pragma unroll
  for (int qn = 0; qn < 4; ++qn)
#pragma unroll
    for (int dt = 0; dt < 4; ++dt)
#pragma unroll
      for (int r = 0; r < 4; ++r) {
        int row = q0 + w * 64 + qn * 16 + quad * 4 + r;
        xg[((size_t)(bh >> 3) * L_ + row) * 512 + h * 64 + dt * 16 + ml] =
            (__bf16)(o[qn][dt][r] * linv[qn][r]);
      }
}

// ---------------------------------------------------------------------------
// Output GEMM: out[16384,512] (fp32) = Xattn(bf16) @ Wo + bo.
// ---------------------------------------------------------------------------
__global__ __launch_bounds__(256) void gemm_out_kernel(
    const __bf16* __restrict__ Xb,
    const __bf16* __restrict__ Wt,
    const float* __restrict__ bo,
    float* __restrict__ out)
{
  __shared__ __align__(16) __bf16 As[4][128][8];
  __shared__ __align__(16) __bf16 Bs[4][128][8];
  const int t = threadIdx.x;
  const int m0 = blockIdx.x * 128, n0 = blockIdx.y * 128;
  const int lane = t & 63, w = t >> 6;
  const int ml = lane & 15, quad = lane >> 4;
  const int wm = w & 1, wn = w >> 1;

  f32x4 acc[4][4];
#pragma unroll
  for (int i = 0; i < 4; ++i)
#pragma unroll
    for (int j = 0; j < 4; ++j) acc[i][j] = (f32x4){0.f, 0.f, 0.f, 0.f};

  for (int k0 = 0; k0 < 512; k0 += 32) {
    __syncthreads();
#pragma unroll
    for (int i = 0; i < 2; ++i) {
      int slot = (w + i * 4) * 64 + lane;
      int ko = slot >> 7, row = slot & 127;
      gl_lds16(&Xb[(size_t)(m0 + row) * 512 + k0 + ko * 8], &As[ko][row][0]);
      gl_lds16(&Wt[(size_t)(n0 + row) * 512 + k0 + ko * 8], &Bs[ko][row][0]);
    }
    __syncthreads();
    bf16x8 a[4], b[4];
#pragma unroll
    for (int mt = 0; mt < 4; ++mt)
      a[mt] = *(const bf16x8*)&As[quad][wm * 64 + mt * 16 + ml][0];
#pragma unroll
    for (int nt = 0; nt < 4; ++nt)
      b[nt] = *(const bf16x8*)&Bs[quad][wn * 64 + nt * 16 + ml][0];
#pragma unroll
    for (int mt = 0; mt < 4; ++mt)
#pragma unroll
      for (int nt = 0; nt < 4; ++nt)
        acc[mt][nt] =
            __builtin_amdgcn_mfma_f32_16x16x32_bf16(a[mt], b[nt], acc[mt][nt], 0, 0, 0);
  }

#pragma unroll
  for (int nt = 0; nt < 4; ++nt) {
    int col = n0 + wn * 64 + nt * 16 + ml;
    float bv = bo[col];
#pragma unroll
    for (int mt = 0; mt < 4; ++mt) {
      int row0 = m0 + wm * 64 + mt * 16 + quad * 4;
#pragma unroll
      for (int r = 0; r < 4; ++r)
        out[(size_t)(row0 + r) * 512 + col] = acc[mt][nt][r] + bv;
    }
  }
}

// ---------------------------------------------------------------------------
extern "C" void kernel_launch(void* const* d_in, const int* in_sizes, int n_in,
                              void* d_out, int out_size, void* d_ws, size_t ws_size,
                              hipStream_t stream) {
  const float* inputs_q  = (const float*)d_in[0];
  const float* inputs_kv = (const float*)d_in[1];
  const float* Wq = (const float*)d_in[2];
  const float* bq = (const float*)d_in[3];
  const float* Wk = (const float*)d_in[4];
  const float* bk = (const float*)d_in[5];
  const float* Wv = (const float*)d_in[6];
  const float* bv = (const float*)d_in[7];
  const float* Wo = (const float*)d_in[8];
  const float* bo = (const float*)d_in[9];
  const float* toep = (const float*)d_in[10];
  float* out = (float*)d_out;

  char* ws = (char*)d_ws;
  __bf16* qb = (__bf16*)(ws);
  __bf16* kb = (__bf16*)(ws + 16777216);
  __bf16* vb = (__bf16*)(ws + 33554432);
  __bf16* xb = (__bf16*)(ws + 50331648);
  __bf16* Wt = (__bf16*)(ws + 67108864);

  wt_kernel<<<dim3(16, 16, 4), 256, 0, stream>>>(Wq, Wk, Wv, Wo, Wt);
  gemm_proj_kernel<<<dim3(128, 12), 256, 0, stream>>>(
      inputs_q, inputs_kv, Wt, bq, bk, bv, qb, kb, vb);
  attn_kernel<<<dim3(512), 256, 0, stream>>>(qb, kb, vb, toep, xb);
  gemm_out_kernel<<<dim3(128, 4), 256, 0, stream>>>(xb, Wt + 3 * 262144, bo, out);
}